// Round 13
// baseline (803.346 us; speedup 1.0000x reference)
//
#include <hip/hip_runtime.h>

#define IN_DIM 128
#define HID 64

// ---------------- bucket histogram: per-block partials ----------------
__global__ __launch_bounds__(256) void k_bin_count(const int* __restrict__ dst, int E,
                                                   int* __restrict__ hist2d) {
    __shared__ int h[256];
    int tid = threadIdx.x;
    h[tid] = 0;
    __syncthreads();
    int base = blockIdx.x * 4096;
    int end = min(base + 4096, E);
    for (int i = base + tid; i < end; i += 256) atomicAdd(&h[dst[i] >> 8], 1);
    __syncthreads();
    hist2d[blockIdx.x * 256 + tid] = h[tid];
}

// ---------------- bucket exclusive scan (sums 2D partials) + gcur=0 + sentinel ----------------
__global__ __launch_bounds__(256) void k_bucket_scan(const int* __restrict__ hist2d, int eblk,
                                                     int* __restrict__ bbase,
                                                     int* __restrict__ gcur, int E) {
    int tid = threadIdx.x, lane = tid & 63, wid = tid >> 6;
    int v = 0;
    for (int k = 0; k < eblk; ++k) v += hist2d[k * 256 + tid];
    int orig = v;
    for (int off = 1; off < 64; off <<= 1) {
        int t = __shfl_up(v, off);
        if (lane >= off) v += t;
    }
    __shared__ int ws[4];
    if (lane == 63) ws[wid] = v;
    __syncthreads();
    int woff = 0;
    for (int w = 0; w < wid; ++w) woff += ws[w];
    bbase[tid] = woff + v - orig;
    gcur[tid] = 0;
    if (tid == 0) bbase[256] = E;
}

// ---------------- bucket-chunked scatter: ebuf packed (dstlo<<16|src). N < 65536 ----------------
__global__ __launch_bounds__(512) void k_bin_scatter(const int* __restrict__ src,
                                                     const int* __restrict__ dst, int E,
                                                     const int* __restrict__ bbase,
                                                     int* __restrict__ gcur,
                                                     unsigned* __restrict__ ebuf) {
    __shared__ int hist[256];
    __shared__ int gbase[256];
    int tid = threadIdx.x;
    for (int i = tid; i < 256; i += 512) hist[i] = 0;
    __syncthreads();
    int base = blockIdx.x * 4096;
    int pk[8], bkt[8], rnk[8];
#pragma unroll
    for (int i = 0; i < 8; ++i) {
        int e = base + tid + i * 512;
        if (e < E) {
            int s = src[e];
            int d = dst[e];
            bkt[i] = d >> 8;
            pk[i] = ((d & 255) << 16) | s;
            rnk[i] = atomicAdd(&hist[bkt[i]], 1);
        } else {
            bkt[i] = -1;
        }
    }
    __syncthreads();
    for (int b = tid; b < 256; b += 512) {
        int c = hist[b];
        if (c > 0) gbase[b] = bbase[b] + atomicAdd(&gcur[b], c);
    }
    __syncthreads();
#pragma unroll
    for (int i = 0; i < 8; ++i) {
        if (bkt[i] >= 0) ebuf[gbase[bkt[i]] + rnk[i]] = (unsigned)pk[i];
    }
}

// ---------------- per-bucket degree -> dis = rsqrt(deg+1) ----------------
__global__ __launch_bounds__(256) void k_deg_dis(const unsigned* __restrict__ ebuf,
                                                 const int* __restrict__ bbase, int N,
                                                 float* __restrict__ dis) {
    __shared__ int ldeg[256];
    int tid = threadIdx.x;
    ldeg[tid] = 0;
    __syncthreads();
    int estart = bbase[blockIdx.x], eend = bbase[blockIdx.x + 1];
    for (int e = estart + tid; e < eend; e += 256) atomicAdd(&ldeg[(ebuf[e] >> 16) & 255], 1);
    __syncthreads();
    int node = (blockIdx.x << 8) + tid;
    if (node < N) dis[node] = rsqrtf((float)(ldeg[tid] + 1));
}

// ---------------- K-chunked tiled GEMM: out[r][c] = dis[r]*sum_k X[r][k]*W[k][c] ----------------
template <int K>
__global__ __launch_bounds__(256) void k_gemm_scale(const float* __restrict__ X,
                                                    const float* __restrict__ W,
                                                    const float* __restrict__ dis, int N,
                                                    float* __restrict__ out) {
    constexpr int CH = 64;
    constexpr int CHP = CH + 4;
    constexpr int KC = K / 4;
    __shared__ float Xs[64 * CHP];
    __shared__ float Ws[CH * 64];
    int tid = threadIdx.x;
    int row0 = blockIdx.x * 64;
    int cg = tid & 15;
    int rg = tid >> 4;
    float acc[4][4] = {};
    const float4* Wg = (const float4*)W;
    const float4* Xg = (const float4*)X;
    float4* Ws4 = (float4*)Ws;

#pragma unroll
    for (int k0 = 0; k0 < K; k0 += CH) {
        if (k0) __syncthreads();
        for (int i = tid; i < CH * 16; i += 256) Ws4[i] = Wg[k0 * 16 + i];
        for (int c = tid; c < 64 * 16; c += 256) {
            int r = c >> 4, k4 = c & 15;
            int row = row0 + r;
            float4 vv = make_float4(0.f, 0.f, 0.f, 0.f);
            if (row < N) vv = Xg[(size_t)row * KC + (k0 >> 2) + k4];
            *(float4*)&Xs[r * CHP + k4 * 4] = vv;
        }
        __syncthreads();
#pragma unroll 2
        for (int k = 0; k < CH; k += 4) {
            float4 w0 = *(float4*)&Ws[(k + 0) * 64 + cg * 4];
            float4 w1 = *(float4*)&Ws[(k + 1) * 64 + cg * 4];
            float4 w2 = *(float4*)&Ws[(k + 2) * 64 + cg * 4];
            float4 w3 = *(float4*)&Ws[(k + 3) * 64 + cg * 4];
#pragma unroll
            for (int i = 0; i < 4; ++i) {
                float4 xv = *(float4*)&Xs[(rg * 4 + i) * CHP + k];
                acc[i][0] += xv.x * w0.x + xv.y * w1.x + xv.z * w2.x + xv.w * w3.x;
                acc[i][1] += xv.x * w0.y + xv.y * w1.y + xv.z * w2.y + xv.w * w3.y;
                acc[i][2] += xv.x * w0.z + xv.y * w1.z + xv.z * w2.z + xv.w * w3.z;
                acc[i][3] += xv.x * w0.w + xv.y * w1.w + xv.z * w2.w + xv.w * w3.w;
            }
        }
    }
#pragma unroll
    for (int i = 0; i < 4; ++i) {
        int row = row0 + rg * 4 + i;
        if (row < N) {
            float s = dis[row];
            *(float4*)&out[(size_t)row * 64 + cg * 4] =
                make_float4(acc[i][0] * s, acc[i][1] * s, acc[i][2] * s, acc[i][3] * s);
        }
    }
}

// ---------------- edge-centric LDS-accumulate aggregate ----------------
// One block per 256-node bucket; acc[256][64] in LDS (XOR-swizzled cols).
// 4 threads per edge, each gathers 4 float4 of the source row -> 16 ds_add_f32.
// Epilogue: out = relu(dis[d]*(acc + Hs[d]) + bias); optional fused head.
__global__ __launch_bounds__(1024) void k_agg_lds(const float* __restrict__ Hs,
                                                  const unsigned* __restrict__ ebuf,
                                                  const int* __restrict__ bbase,
                                                  const float* __restrict__ dis,
                                                  const float* __restrict__ bias, int N,
                                                  float* __restrict__ out,
                                                  const float* __restrict__ Wl,
                                                  const float* __restrict__ bl, int do_head) {
    __shared__ float acc[256 * 64];
    const float4* Hs4 = (const float4*)Hs;
    int tid = threadIdx.x;
    int node0 = blockIdx.x << 8;
    float4* acc4 = (float4*)acc;
    float4 zz = make_float4(0.f, 0.f, 0.f, 0.f);
    for (int i = tid; i < 256 * 16; i += 1024) acc4[i] = zz;
    __syncthreads();
    int estart = bbase[blockIdx.x], eend = bbase[blockIdx.x + 1];
    int t4 = tid & 3;
    int cb = t4 * 16;
    for (int e = estart + (tid >> 2); e < eend; e += 256) {
        unsigned u = ebuf[e];
        int dlo = (u >> 16) & 255;
        int s = u & 0xFFFF;
        int q = (dlo & 7) << 2;
        size_t sb = (size_t)s * 16 + t4 * 4;
        float4 z0 = Hs4[sb + 0];
        float4 z1 = Hs4[sb + 1];
        float4 z2 = Hs4[sb + 2];
        float4 z3 = Hs4[sb + 3];
        float* r = &acc[dlo * 64];
        int c0 = (cb + 0) ^ q, c1 = (cb + 4) ^ q, c2 = (cb + 8) ^ q, c3 = (cb + 12) ^ q;
        atomicAdd(&r[c0 + 0], z0.x); atomicAdd(&r[c0 + 1], z0.y);
        atomicAdd(&r[c0 + 2], z0.z); atomicAdd(&r[c0 + 3], z0.w);
        atomicAdd(&r[c1 + 0], z1.x); atomicAdd(&r[c1 + 1], z1.y);
        atomicAdd(&r[c1 + 2], z1.z); atomicAdd(&r[c1 + 3], z1.w);
        atomicAdd(&r[c2 + 0], z2.x); atomicAdd(&r[c2 + 1], z2.y);
        atomicAdd(&r[c2 + 2], z2.z); atomicAdd(&r[c2 + 3], z2.w);
        atomicAdd(&r[c3 + 0], z3.x); atomicAdd(&r[c3 + 1], z3.y);
        atomicAdd(&r[c3 + 2], z3.z); atomicAdd(&r[c3 + 3], z3.w);
    }
    __syncthreads();
    // epilogue: 4 threads per node (t4 covers cols t4*16 .. t4*16+15)
    int nl = tid >> 2;
    int node = node0 + nl;
    if (node >= N) return;
    int q = (nl & 7) << 2;
    float dn = dis[node];
    float4 r[4];
#pragma unroll
    for (int k = 0; k < 4; ++k) {
        int col = cb + 4 * k;
        float4 a = *(float4*)&acc[nl * 64 + (col ^ q)];
        float4 self = Hs4[(size_t)node * 16 + t4 * 4 + k];
        float4 b = ((const float4*)bias)[t4 * 4 + k];
        r[k].x = fmaxf(fmaf(dn, a.x + self.x, b.x), 0.f);
        r[k].y = fmaxf(fmaf(dn, a.y + self.y, b.y), 0.f);
        r[k].z = fmaxf(fmaf(dn, a.z + self.z, b.z), 0.f);
        r[k].w = fmaxf(fmaf(dn, a.w + self.w, b.w), 0.f);
    }
    if (!do_head) {
        float4* o4 = (float4*)out;
#pragma unroll
        for (int k = 0; k < 4; ++k) o4[(size_t)node * 16 + t4 * 4 + k] = r[k];
    } else {
        float p0 = 0.f, p1 = 0.f;
#pragma unroll
        for (int k = 0; k < 4; ++k) {
            int col = cb + 4 * k;
            p0 += r[k].x * Wl[(col + 0) * 2] + r[k].y * Wl[(col + 1) * 2] +
                  r[k].z * Wl[(col + 2) * 2] + r[k].w * Wl[(col + 3) * 2];
            p1 += r[k].x * Wl[(col + 0) * 2 + 1] + r[k].y * Wl[(col + 1) * 2 + 1] +
                  r[k].z * Wl[(col + 2) * 2 + 1] + r[k].w * Wl[(col + 3) * 2 + 1];
        }
        p0 += __shfl_xor(p0, 1); p1 += __shfl_xor(p1, 1);
        p0 += __shfl_xor(p0, 2); p1 += __shfl_xor(p1, 2);
        if (t4 == 0) {
            out[node * 2 + 0] = p0 + bl[0];
            out[node * 2 + 1] = p1 + bl[1];
        }
    }
}

extern "C" void kernel_launch(void* const* d_in, const int* in_sizes, int n_in,
                              void* d_out, int out_size, void* d_ws, size_t ws_size,
                              hipStream_t stream) {
    const float* x  = (const float*)d_in[0];
    const int*   ei = (const int*)d_in[1];
    const float* W1 = (const float*)d_in[2];
    const float* b1 = (const float*)d_in[3];
    const float* W2 = (const float*)d_in[4];
    const float* b2 = (const float*)d_in[5];
    const float* Wl = (const float*)d_in[6];
    const float* bl = (const float*)d_in[7];

    const int N = in_sizes[0] / IN_DIM;   // 50000 (< 65536 required by packing)
    const int E = in_sizes[1] / 2;        // 800000
    const int* src = ei;
    const int* dst = ei + E;

    char* ws = (char*)d_ws;
    size_t off = 0;
    auto alloc = [&](size_t bytes) -> void* {
        void* p = ws + off;
        off = (off + bytes + 255) & ~(size_t)255;
        return p;
    };
    const int eblk = (E + 4095) / 4096;  // 196
    const int nb = (N + 255) / 256;      // 196
    int*      hist2d = (int*)alloc((size_t)eblk * 256 * 4);
    int*      bbase  = (int*)alloc(257 * 4);
    int*      gcur   = (int*)alloc(256 * 4);
    float*    dis    = (float*)alloc((size_t)N * 4);
    unsigned* ebuf   = (unsigned*)alloc((size_t)E * 4);  // persists through both aggregates
    float*    bufA   = (float*)alloc((size_t)N * HID * 4);
    float*    bufB   = (float*)alloc((size_t)N * HID * 4);

    k_bin_count<<<eblk, 256, 0, stream>>>(dst, E, hist2d);
    k_bucket_scan<<<1, 256, 0, stream>>>(hist2d, eblk, bbase, gcur, E);
    k_bin_scatter<<<eblk, 512, 0, stream>>>(src, dst, E, bbase, gcur, ebuf);
    k_deg_dis<<<nb, 256, 0, stream>>>(ebuf, bbase, N, dis);

    const int gblk = (N + 63) / 64;  // 782
    k_gemm_scale<IN_DIM><<<gblk, 256, 0, stream>>>(x, W1, dis, N, bufA);
    k_agg_lds<<<nb, 1024, 0, stream>>>(bufA, ebuf, bbase, dis, b1, N, bufB, nullptr, nullptr, 0);
    k_gemm_scale<HID><<<gblk, 256, 0, stream>>>(bufB, W2, dis, N, bufA);
    k_agg_lds<<<nb, 1024, 0, stream>>>(bufA, ebuf, bbase, dis, b2, N, (float*)d_out, Wl, bl, 1);
}

// Round 14
// 144.485 us; speedup vs baseline: 5.5601x; 5.5601x over previous
//
#include <hip/hip_runtime.h>
#include <hip/hip_fp16.h>

#define IN_DIM 128
#define HID 64
#define STAGE_CAP 12288

// ---------------- bucket histogram: per-block partials (no global atomics/memset) ----------------
__global__ __launch_bounds__(256) void k_bin_count(const int* __restrict__ dst, int E,
                                                   int* __restrict__ hist2d) {
    __shared__ int h[256];
    int tid = threadIdx.x;
    h[tid] = 0;
    __syncthreads();
    int base = blockIdx.x * 4096;
    int end = min(base + 4096, E);
    for (int i = base + tid; i < end; i += 256) atomicAdd(&h[dst[i] >> 8], 1);
    __syncthreads();
    hist2d[blockIdx.x * 256 + tid] = h[tid];
}

// ---------------- bucket exclusive scan + gcur=0 + sentinels ----------------
__global__ __launch_bounds__(256) void k_bucket_scan(const int* __restrict__ hist2d, int eblk,
                                                     int* __restrict__ bbase,
                                                     int* __restrict__ gcur,
                                                     int* __restrict__ row_start, int N, int E) {
    int tid = threadIdx.x, lane = tid & 63, wid = tid >> 6;
    int v = 0;
    for (int k = 0; k < eblk; ++k) v += hist2d[k * 256 + tid];
    int orig = v;
    for (int off = 1; off < 64; off <<= 1) {
        int t = __shfl_up(v, off);
        if (lane >= off) v += t;
    }
    __shared__ int ws[4];
    if (lane == 63) ws[wid] = v;
    __syncthreads();
    int woff = 0;
    for (int w = 0; w < wid; ++w) woff += ws[w];
    bbase[tid] = woff + v - orig;
    gcur[tid] = 0;
    if (tid == 0) {
        bbase[256] = E;
        row_start[N] = E;
    }
}

// ---------------- bucket-chunked scatter (N < 65536) ----------------
__global__ __launch_bounds__(512) void k_bin_scatter(const int* __restrict__ src,
                                                     const int* __restrict__ dst, int E,
                                                     const int* __restrict__ bbase,
                                                     int* __restrict__ gcur,
                                                     unsigned* __restrict__ ebuf) {
    __shared__ int hist[256];
    __shared__ int gbase[256];
    int tid = threadIdx.x;
    for (int i = tid; i < 256; i += 512) hist[i] = 0;
    __syncthreads();
    int base = blockIdx.x * 4096;
    int pk[8], bkt[8], rnk[8];
#pragma unroll
    for (int i = 0; i < 8; ++i) {
        int e = base + tid + i * 512;
        if (e < E) {
            int s = src[e];
            int d = dst[e];
            bkt[i] = d >> 8;
            pk[i] = ((d & 255) << 16) | s;
            rnk[i] = atomicAdd(&hist[bkt[i]], 1);
        } else {
            bkt[i] = -1;
        }
    }
    __syncthreads();
    for (int b = tid; b < 256; b += 512) {
        int c = hist[b];
        if (c > 0) gbase[b] = bbase[b] + atomicAdd(&gcur[b], c);
    }
    __syncthreads();
#pragma unroll
    for (int i = 0; i < 8; ++i) {
        if (bkt[i] >= 0) ebuf[gbase[bkt[i]] + rnk[i]] = (unsigned)pk[i];
    }
}

// ---------------- bin_sort: degree+scan -> row_start, dis ; LDS counting sort -> csr_src ----------------
__global__ __launch_bounds__(512) void k_bin_sort(const unsigned* __restrict__ ebuf,
                                                  const int* __restrict__ bbase, int N, int E,
                                                  int* __restrict__ row_start,
                                                  float* __restrict__ dis,
                                                  int* __restrict__ csr_src) {
    __shared__ int ldeg[256];
    __shared__ int loff[256];
    __shared__ int lcur[256];
    __shared__ int wsum[8];
    __shared__ unsigned short stage[STAGE_CAP];
    int tid = threadIdx.x;
    int node0 = blockIdx.x << 8;
    int nnode = min(256, N - node0);
    for (int i = tid; i < 256; i += 512) {
        ldeg[i] = 0;
        lcur[i] = 0;
    }
    __syncthreads();
    int bstart = bbase[blockIdx.x];
    int bend = bbase[blockIdx.x + 1];
    int cnt = bend - bstart;
    for (int i = tid; i < cnt; i += 512) {
        unsigned u = ebuf[bstart + i];
        atomicAdd(&ldeg[(u >> 16) & 255], 1);
    }
    __syncthreads();
    int lane = tid & 63, wid = tid >> 6;
    int v = 0, orig = 0;
    if (tid < 256) {
        orig = ldeg[tid];
        v = orig;
    }
    for (int off = 1; off < 64; off <<= 1) {
        int t = __shfl_up(v, off);
        if (lane >= off) v += t;
    }
    if (lane == 63) wsum[wid] = v;
    __syncthreads();
    if (tid < 256) {
        int woff = 0;
        for (int w = 0; w < wid && w < 4; ++w) woff += wsum[w];
        int excl = woff + v - orig;
        loff[tid] = excl;
        if (tid < nnode) {
            row_start[node0 + tid] = bstart + excl;
            dis[node0 + tid] = rsqrtf((float)(orig + 1));
        }
    }
    __syncthreads();
    if (cnt <= STAGE_CAP) {
        for (int i = tid; i < cnt; i += 512) {
            unsigned u = ebuf[bstart + i];
            int dlo = (u >> 16) & 255;
            int pos = loff[dlo] + atomicAdd(&lcur[dlo], 1);
            stage[pos] = (unsigned short)(u & 0xFFFF);
        }
        __syncthreads();
        for (int i = tid; i < cnt; i += 512) csr_src[bstart + i] = (int)stage[i];
    } else {
        for (int i = tid; i < cnt; i += 512) {
            unsigned u = ebuf[bstart + i];
            int dlo = (u >> 16) & 255;
            int pos = bstart + loff[dlo] + atomicAdd(&lcur[dlo], 1);
            csr_src[pos] = (int)(u & 0xFFFF);
        }
    }
}

// ---------------- K-chunked tiled GEMM, fp16 output: out[r][c] = half(dis[r]*sum_k X@W) ----------------
template <int K>
__global__ __launch_bounds__(256) void k_gemm_scale_h(const float* __restrict__ X,
                                                      const float* __restrict__ W,
                                                      const float* __restrict__ dis, int N,
                                                      __half* __restrict__ out) {
    constexpr int CH = 64;
    constexpr int CHP = CH + 4;
    constexpr int KC = K / 4;
    __shared__ float Xs[64 * CHP];
    __shared__ float Ws[CH * 64];
    int tid = threadIdx.x;
    int row0 = blockIdx.x * 64;
    int cg = tid & 15;
    int rg = tid >> 4;
    float acc[4][4] = {};
    const float4* Wg = (const float4*)W;
    const float4* Xg = (const float4*)X;
    float4* Ws4 = (float4*)Ws;

#pragma unroll
    for (int k0 = 0; k0 < K; k0 += CH) {
        if (k0) __syncthreads();
        for (int i = tid; i < CH * 16; i += 256) Ws4[i] = Wg[k0 * 16 + i];
        for (int c = tid; c < 64 * 16; c += 256) {
            int r = c >> 4, k4 = c & 15;
            int row = row0 + r;
            float4 vv = make_float4(0.f, 0.f, 0.f, 0.f);
            if (row < N) vv = Xg[(size_t)row * KC + (k0 >> 2) + k4];
            *(float4*)&Xs[r * CHP + k4 * 4] = vv;
        }
        __syncthreads();
#pragma unroll 2
        for (int k = 0; k < CH; k += 4) {
            float4 w0 = *(float4*)&Ws[(k + 0) * 64 + cg * 4];
            float4 w1 = *(float4*)&Ws[(k + 1) * 64 + cg * 4];
            float4 w2 = *(float4*)&Ws[(k + 2) * 64 + cg * 4];
            float4 w3 = *(float4*)&Ws[(k + 3) * 64 + cg * 4];
#pragma unroll
            for (int i = 0; i < 4; ++i) {
                float4 xv = *(float4*)&Xs[(rg * 4 + i) * CHP + k];
                acc[i][0] += xv.x * w0.x + xv.y * w1.x + xv.z * w2.x + xv.w * w3.x;
                acc[i][1] += xv.x * w0.y + xv.y * w1.y + xv.z * w2.y + xv.w * w3.y;
                acc[i][2] += xv.x * w0.z + xv.y * w1.z + xv.z * w2.z + xv.w * w3.z;
                acc[i][3] += xv.x * w0.w + xv.y * w1.w + xv.z * w2.w + xv.w * w3.w;
            }
        }
    }
#pragma unroll
    for (int i = 0; i < 4; ++i) {
        int row = row0 + rg * 4 + i;
        if (row < N) {
            float s = dis[row];
            __half2 h01 = __floats2half2_rn(acc[i][0] * s, acc[i][1] * s);
            __half2 h23 = __floats2half2_rn(acc[i][2] * s, acc[i][3] * s);
            uint2 pk = make_uint2(*(unsigned*)&h01, *(unsigned*)&h23);
            ((uint2*)out)[(size_t)row * 16 + cg] = pk;  // row = 16 uint2 (128B)
        }
    }
}

__device__ __forceinline__ void unpack8(float4 raw, float* f) {
    const __half2* hp = (const __half2*)&raw;
#pragma unroll
    for (int k = 0; k < 4; ++k) {
        float2 t2 = __half22float2(hp[k]);
        f[2 * k] = t2.x;
        f[2 * k + 1] = t2.y;
    }
}

// ---------------- gather-aggregate v8 (fp16 rows): 1 load/lane/edge, 4 edges in flight ----------------
// lane = g*8 + t ; subgroup g handles edges jb+{0,8,16,24}+g; lane covers halves [8t..8t+7]
__global__ __launch_bounds__(256) void k_aggregate_h(const __half* __restrict__ Hs,
                                                     const int* __restrict__ row_start,
                                                     const int* __restrict__ csr_src,
                                                     const float* __restrict__ dis,
                                                     const float* __restrict__ bias, int N,
                                                     float* __restrict__ out) {
    const float4* H4 = (const float4*)Hs;  // row = 8 float4 (128B)
    int wave = threadIdx.x >> 6, lane = threadIdx.x & 63;
    int node = blockIdx.x * 4 + wave;
    if (node >= N) return;
    int t = lane & 7, g = lane >> 3;
    float a[8] = {};
    if (g == 0) unpack8(H4[(size_t)node * 8 + t], a);  // self loop
    int e0 = row_start[node], e1 = row_start[node + 1];
    for (int eb = e0; eb < e1; eb += 64) {
        int cnt = min(64, e1 - eb);
        int sv = (eb + lane < e1) ? csr_src[eb + lane] : 0;
        for (int jb = 0; jb < cnt; jb += 32) {
            int i0 = jb + g, i1 = jb + 8 + g, i2 = jb + 16 + g, i3 = jb + 24 + g;
            int s0 = __shfl(sv, i0 < cnt ? i0 : 0);
            int s1 = __shfl(sv, i1 < cnt ? i1 : 0);
            int s2 = __shfl(sv, i2 < cnt ? i2 : 0);
            int s3 = __shfl(sv, i3 < cnt ? i3 : 0);
            float4 r0 = H4[(size_t)s0 * 8 + t];
            float4 r1 = H4[(size_t)s1 * 8 + t];
            float4 r2 = H4[(size_t)s2 * 8 + t];
            float4 r3 = H4[(size_t)s3 * 8 + t];
            float z[8];
            if (i0 < cnt) {
                unpack8(r0, z);
#pragma unroll
                for (int k = 0; k < 8; ++k) a[k] += z[k];
            }
            if (i1 < cnt) {
                unpack8(r1, z);
#pragma unroll
                for (int k = 0; k < 8; ++k) a[k] += z[k];
            }
            if (i2 < cnt) {
                unpack8(r2, z);
#pragma unroll
                for (int k = 0; k < 8; ++k) a[k] += z[k];
            }
            if (i3 < cnt) {
                unpack8(r3, z);
#pragma unroll
                for (int k = 0; k < 8; ++k) a[k] += z[k];
            }
        }
    }
#pragma unroll
    for (int off = 8; off < 64; off <<= 1) {
#pragma unroll
        for (int k = 0; k < 8; ++k) a[k] += __shfl_xor(a[k], off);
    }
    float sc = dis[node];
    float4 b0 = ((const float4*)bias)[2 * t];
    float4 b1 = ((const float4*)bias)[2 * t + 1];
    float4 v0, v1;
    v0.x = fmaxf(a[0] * sc + b0.x, 0.f); v0.y = fmaxf(a[1] * sc + b0.y, 0.f);
    v0.z = fmaxf(a[2] * sc + b0.z, 0.f); v0.w = fmaxf(a[3] * sc + b0.w, 0.f);
    v1.x = fmaxf(a[4] * sc + b1.x, 0.f); v1.y = fmaxf(a[5] * sc + b1.y, 0.f);
    v1.z = fmaxf(a[6] * sc + b1.z, 0.f); v1.w = fmaxf(a[7] * sc + b1.w, 0.f);
    if (g == 0) {
        float4* o4 = (float4*)out;
        o4[(size_t)node * 16 + 2 * t] = v0;
        o4[(size_t)node * 16 + 2 * t + 1] = v1;
    }
}

// ---------------- aggregate v8 + fused head ----------------
__global__ __launch_bounds__(256) void k_aggregate_head_h(const __half* __restrict__ Hs,
                                                          const int* __restrict__ row_start,
                                                          const int* __restrict__ csr_src,
                                                          const float* __restrict__ dis,
                                                          const float* __restrict__ bias,
                                                          const float* __restrict__ Wl,
                                                          const float* __restrict__ bl, int N,
                                                          float* __restrict__ out) {
    const float4* H4 = (const float4*)Hs;
    int wave = threadIdx.x >> 6, lane = threadIdx.x & 63;
    int node = blockIdx.x * 4 + wave;
    if (node >= N) return;
    int t = lane & 7, g = lane >> 3;
    float a[8] = {};
    if (g == 0) unpack8(H4[(size_t)node * 8 + t], a);
    int e0 = row_start[node], e1 = row_start[node + 1];
    for (int eb = e0; eb < e1; eb += 64) {
        int cnt = min(64, e1 - eb);
        int sv = (eb + lane < e1) ? csr_src[eb + lane] : 0;
        for (int jb = 0; jb < cnt; jb += 32) {
            int i0 = jb + g, i1 = jb + 8 + g, i2 = jb + 16 + g, i3 = jb + 24 + g;
            int s0 = __shfl(sv, i0 < cnt ? i0 : 0);
            int s1 = __shfl(sv, i1 < cnt ? i1 : 0);
            int s2 = __shfl(sv, i2 < cnt ? i2 : 0);
            int s3 = __shfl(sv, i3 < cnt ? i3 : 0);
            float4 r0 = H4[(size_t)s0 * 8 + t];
            float4 r1 = H4[(size_t)s1 * 8 + t];
            float4 r2 = H4[(size_t)s2 * 8 + t];
            float4 r3 = H4[(size_t)s3 * 8 + t];
            float z[8];
            if (i0 < cnt) {
                unpack8(r0, z);
#pragma unroll
                for (int k = 0; k < 8; ++k) a[k] += z[k];
            }
            if (i1 < cnt) {
                unpack8(r1, z);
#pragma unroll
                for (int k = 0; k < 8; ++k) a[k] += z[k];
            }
            if (i2 < cnt) {
                unpack8(r2, z);
#pragma unroll
                for (int k = 0; k < 8; ++k) a[k] += z[k];
            }
            if (i3 < cnt) {
                unpack8(r3, z);
#pragma unroll
                for (int k = 0; k < 8; ++k) a[k] += z[k];
            }
        }
    }
#pragma unroll
    for (int off = 8; off < 64; off <<= 1) {
#pragma unroll
        for (int k = 0; k < 8; ++k) a[k] += __shfl_xor(a[k], off);
    }
    float sc = dis[node];
    float4 b0 = ((const float4*)bias)[2 * t];
    float4 b1 = ((const float4*)bias)[2 * t + 1];
    float v[8];
    v[0] = fmaxf(a[0] * sc + b0.x, 0.f); v[1] = fmaxf(a[1] * sc + b0.y, 0.f);
    v[2] = fmaxf(a[2] * sc + b0.z, 0.f); v[3] = fmaxf(a[3] * sc + b0.w, 0.f);
    v[4] = fmaxf(a[4] * sc + b1.x, 0.f); v[5] = fmaxf(a[5] * sc + b1.y, 0.f);
    v[6] = fmaxf(a[6] * sc + b1.z, 0.f); v[7] = fmaxf(a[7] * sc + b1.w, 0.f);
    float p0 = 0.f, p1 = 0.f;
#pragma unroll
    for (int k = 0; k < 8; ++k) {
        int c = 8 * t + k;
        p0 += v[k] * Wl[c * 2];
        p1 += v[k] * Wl[c * 2 + 1];
    }
    p0 += __shfl_xor(p0, 1); p1 += __shfl_xor(p1, 1);
    p0 += __shfl_xor(p0, 2); p1 += __shfl_xor(p1, 2);
    p0 += __shfl_xor(p0, 4); p1 += __shfl_xor(p1, 4);
    if (lane == 0) {
        out[node * 2 + 0] = p0 + bl[0];
        out[node * 2 + 1] = p1 + bl[1];
    }
}

extern "C" void kernel_launch(void* const* d_in, const int* in_sizes, int n_in,
                              void* d_out, int out_size, void* d_ws, size_t ws_size,
                              hipStream_t stream) {
    const float* x  = (const float*)d_in[0];
    const int*   ei = (const int*)d_in[1];
    const float* W1 = (const float*)d_in[2];
    const float* b1 = (const float*)d_in[3];
    const float* W2 = (const float*)d_in[4];
    const float* b2 = (const float*)d_in[5];
    const float* Wl = (const float*)d_in[6];
    const float* bl = (const float*)d_in[7];

    const int N = in_sizes[0] / IN_DIM;   // 50000 (< 65536 required by packing)
    const int E = in_sizes[1] / 2;        // 800000
    const int* src = ei;
    const int* dst = ei + E;

    char* ws = (char*)d_ws;
    size_t off = 0;
    auto alloc = [&](size_t bytes) -> void* {
        void* p = ws + off;
        off = (off + bytes + 255) & ~(size_t)255;
        return p;
    };
    const int eblk = (E + 4095) / 4096;  // 196
    const int nb = (N + 255) / 256;      // 196
    int*    hist2d    = (int*)alloc((size_t)eblk * 256 * 4);
    int*    bbase     = (int*)alloc(257 * 4);
    int*    gcur      = (int*)alloc(256 * 4);
    int*    row_start = (int*)alloc(((size_t)N + 1) * 4);
    float*  dis       = (float*)alloc((size_t)N * 4);
    int*    csr_src   = (int*)alloc((size_t)E * 4);
    __half* hbuf      = (__half*)alloc((size_t)N * HID * 2);  // fp16 Hs
    float*  bufB      = (float*)alloc((size_t)N * HID * 4);
    unsigned* ebuf    = (unsigned*)hbuf;  // alias: consumed by bin_sort before gemm1 writes hbuf

    k_bin_count<<<eblk, 256, 0, stream>>>(dst, E, hist2d);
    k_bucket_scan<<<1, 256, 0, stream>>>(hist2d, eblk, bbase, gcur, row_start, N, E);
    k_bin_scatter<<<eblk, 512, 0, stream>>>(src, dst, E, bbase, gcur, ebuf);
    k_bin_sort<<<nb, 512, 0, stream>>>(ebuf, bbase, N, E, row_start, dis, csr_src);

    const int gblk = (N + 63) / 64;  // 782
    const int nblk = (N + 3) / 4;
    k_gemm_scale_h<IN_DIM><<<gblk, 256, 0, stream>>>(x, W1, dis, N, hbuf);
    k_aggregate_h<<<nblk, 256, 0, stream>>>(hbuf, row_start, csr_src, dis, b1, N, bufB);
    k_gemm_scale_h<HID><<<gblk, 256, 0, stream>>>(bufB, W2, dis, N, hbuf);
    k_aggregate_head_h<<<nblk, 256, 0, stream>>>(hbuf, row_start, csr_src, dis, b2, Wl, bl, N,
                                                 (float*)d_out);
}